// Round 1
// baseline (184.468 us; speedup 1.0000x reference)
//
#include <hip/hip_runtime.h>

// AFM layer, MI355X gfx950.
// out[b] = sum_p attn_p * s_p,  s_p = sum_d x[i,d]x[j,d]p[d]
// logits via MFMA 32x32x16 f16: A = W1^T (preloaded const frags), B = prod-frag
// built in-register from f16 x in LDS. One wave per batch element.

typedef _Float16 f16;
typedef f16 f16x8 __attribute__((ext_vector_type(8)));
typedef f16 f16x4 __attribute__((ext_vector_type(4)));
typedef f16 f16x2 __attribute__((ext_vector_type(2)));
typedef float fx16 __attribute__((ext_vector_type(16)));

#define NF 40
#define DD 64
#define NB 8192

__global__ __launch_bounds__(256, 2) void afm_kernel(
    const float* __restrict__ x,   // [8192,40,64]
    const float* __restrict__ W1,  // [64,32]
    const float* __restrict__ b1,  // [32]
    const float* __restrict__ w2,  // [32]
    const float* __restrict__ p,   // [64]
    float* __restrict__ out)       // [8192]
{
    // 64 rows (40 real + zero pad to 64) x 64 d, f16, per wave
    __shared__ f16 xh[4][64 * 64];

    const int wid  = threadIdx.x >> 6;
    const int lane = threadIdx.x & 63;
    const int b    = blockIdx.x * 4 + wid;
    f16* Xs = &xh[wid][0];

    // ---- stage x[b] -> LDS f16 (coalesced float4 loads) ----
    const float4* xb = (const float4*)(x + (size_t)b * (NF * DD));
#pragma unroll
    for (int t = 0; t < 10; ++t) {
        int idx = t * 64 + lane;               // 640 float4 total
        float4 v = xb[idx];
        f16x4 h;
        h.x = (f16)v.x; h.y = (f16)v.y; h.z = (f16)v.z; h.w = (f16)v.w;
        *(f16x4*)(Xs + idx * 4) = h;
    }
    // zero rows 40..63 (elements 2560..4095)
    f16x4 z = {};
#pragma unroll
    for (int t = 0; t < 6; ++t) {
        int idx = 640 + t * 64 + lane;
        *(f16x4*)(Xs + idx * 4) = z;
    }
    __syncthreads();

    const int nl = lane & 31;   // i-slot (B-frag n, C col)
    const int hh = lane >> 5;   // wave half
    const int h8 = hh * 8;      // k sub-block

    // ---- A-frags: W1^T, A[m=a=nl][k = h8+j], d = kt*16 + h8 + j ----
    f16x8 w1f[4];
#pragma unroll
    for (int kt = 0; kt < 4; ++kt)
#pragma unroll
        for (int j = 0; j < 8; ++j)
            w1f[kt][j] = (f16)W1[(kt * 16 + h8 + j) * 32 + nl];

    // ---- p packed to match prod-frag element order ----
    f16x2 pp[4][4];
#pragma unroll
    for (int kt = 0; kt < 4; ++kt)
#pragma unroll
        for (int j2 = 0; j2 < 4; ++j2) {
            pp[kt][j2].x = (f16)p[kt * 16 + h8 + 2 * j2];
            pp[kt][j2].y = (f16)p[kt * 16 + h8 + 2 * j2 + 1];
        }

    // ---- b1/w2 per C-frag row: a(reg) = (reg&3) + 8*(reg>>2) + 4*hh ----
    float b1v[16], w2v[16];
#pragma unroll
    for (int r = 0; r < 16; ++r) {
        int a = (r & 3) + 8 * (r >> 2) + 4 * hh;
        b1v[r] = b1[a];
        w2v[r] = w2[a];
    }

    float accW = 0.f, accWS = 0.f;

#pragma unroll
    for (int ig = 0; ig < 2; ++ig) {
        const int i = ig * 32 + nl;           // this lane's field i (may be >=40: auto-masked)
        // xi frags (held in regs across the j loop)
        f16x8 xif[4];
#pragma unroll
        for (int kt = 0; kt < 4; ++kt)
            xif[kt] = *(const f16x8*)(Xs + i * 64 + kt * 16 + h8);

        const int j0 = ig * 32 + 1;           // first j with any valid lane
        for (int j = j0; j < NF; ++j) {
            fx16 C;
#pragma unroll
            for (int r = 0; r < 16; ++r) C[r] = b1v[r];   // fold b1 into accumulator init
            float sp = 0.f;
#pragma unroll
            for (int kt = 0; kt < 4; ++kt) {
                f16x8 xj = *(const f16x8*)(Xs + j * 64 + kt * 16 + h8);  // broadcast read
                f16x8 pr = xif[kt] * xj;                                  // v_pk_mul_f16
                f16x2 t0; t0.x = pr[0]; t0.y = pr[1];
                f16x2 t1; t1.x = pr[2]; t1.y = pr[3];
                f16x2 t2; t2.x = pr[4]; t2.y = pr[5];
                f16x2 t3; t3.x = pr[6]; t3.y = pr[7];
                sp = __builtin_amdgcn_fdot2(t0, pp[kt][0], sp, false);
                sp = __builtin_amdgcn_fdot2(t1, pp[kt][1], sp, false);
                sp = __builtin_amdgcn_fdot2(t2, pp[kt][2], sp, false);
                sp = __builtin_amdgcn_fdot2(t3, pp[kt][3], sp, false);
                C = __builtin_amdgcn_mfma_f32_32x32x16_f16(w1f[kt], pr, C, 0, 0, 0);
            }
            // logit partial: relu(h)·w2 over this lane's 16 a-rows
            float l = 0.f;
#pragma unroll
            for (int r = 0; r < 16; ++r) {
                float hv = fmaxf(C[r], 0.f);
                l = fmaf(hv, w2v[r], l);
            }
            l  += __shfl_xor(l, 32);    // combine the two a-halves
            sp += __shfl_xor(sp, 32);   // combine the two k-halves
            // online (max-free) softmax accumulation; invalid lanes masked
            bool valid = (i < j);
            float w = valid ? __expf(l) : 0.f;
            accW += w;
            accWS = fmaf(w, sp, accWS);
        }
    }

    // reduce across the 32 i-slots (halves already identical)
#pragma unroll
    for (int m = 16; m >= 1; m >>= 1) {
        accW  += __shfl_xor(accW, m);
        accWS += __shfl_xor(accWS, m);
    }
    if (lane == 0) out[b] = accWS / accW;
}

extern "C" void kernel_launch(void* const* d_in, const int* in_sizes, int n_in,
                              void* d_out, int out_size, void* d_ws, size_t ws_size,
                              hipStream_t stream) {
    const float* x  = (const float*)d_in[0];
    const float* W1 = (const float*)d_in[1];
    const float* b1 = (const float*)d_in[2];
    const float* w2 = (const float*)d_in[3];
    const float* p  = (const float*)d_in[4];
    float* out = (float*)d_out;
    dim3 grid(NB / 4), block(256);
    hipLaunchKernelGGL(afm_kernel, grid, block, 0, stream, x, W1, b1, w2, p, out);
}

// Round 2
// 152.969 us; speedup vs baseline: 1.2059x; 1.2059x over previous
//
#include <hip/hip_runtime.h>

// AFM layer, MI355X gfx950.
// out[b] = sum_p attn_p * s_p,  s_p = sum_d x[i,d]x[j,d]p[d]
// Pair enumeration (one wave per batch, 25 MFMA iterations, 780/800 slots used):
//   Phase A: 32-triangle via circular rotation: t=1..15 all lanes (nl,(nl+t)&31),
//            t=16 lanes nl<16. prod is symmetric so pair order never matters.
//   Phase B: j=32..39 broadcast, i=nl<32<=j always valid (8 iters, 256 pairs).
//   Phase C: 8-triangle of fields 32..39 (28 pairs, 1 iter, closed-form unrank).
// Logits via MFMA 32x32x16 f16: A=W1^T const frags, B=prod built in-register.
// b1 folded via MFMA C-operand chaining (no per-iter accumulator init).
// LDS row stride 76 f16 (152 B): bank = 6*row mod 32 -> b64 reads conflict-free.

typedef _Float16 f16;
typedef f16 f16x2 __attribute__((ext_vector_type(2)));
typedef f16 f16x4 __attribute__((ext_vector_type(4)));
typedef f16 f16x8 __attribute__((ext_vector_type(8)));
typedef float fx16 __attribute__((ext_vector_type(16)));

#define NF 40
#define NB 8192
#define STR 76   // f16 elements per LDS row (152 B)

union V8 { f16x8 v8; f16x4 v4[2]; f16x2 v2[4]; };

__global__ __launch_bounds__(256, 4) void afm_kernel(
    const float* __restrict__ x,   // [8192,40,64]
    const float* __restrict__ W1,  // [64,32]
    const float* __restrict__ b1,  // [32]
    const float* __restrict__ w2,  // [32]
    const float* __restrict__ p,   // [64]
    float* __restrict__ out)       // [8192]
{
    __shared__ f16 xh[4][NF * STR];   // 4 batches x 40 rows x 76 f16 = 24,320 B

    const int wid  = threadIdx.x >> 6;
    const int lane = threadIdx.x & 63;
    const int b    = blockIdx.x * 4 + wid;
    f16* Xs = &xh[wid][0];

    // ---- stage x[b] -> LDS f16, stride-76 rows (coalesced float4 loads) ----
    const float4* xb = (const float4*)(x + (size_t)b * (NF * 64));
#pragma unroll
    for (int t = 0; t < 10; ++t) {
        int idx = t * 64 + lane;              // 640 float4 total
        float4 v = xb[idx];
        f16x4 h = { (f16)v.x, (f16)v.y, (f16)v.z, (f16)v.w };
        int r = idx >> 4;                      // row = idx/16
        int d = (idx & 15) * 4;                // col
        *(f16x4*)(Xs + r * STR + d) = h;       // 8B aligned (152r + 2d, d%4==0)
    }
    __syncthreads();

    const int nl = lane & 31;   // MFMA column / field index base
    const int hh = lane >> 5;   // wave half -> k sub-block + a-row group
    const int h8 = hh * 8;

    // ---- A-frags: W1^T, A[m=a][k=h8+j], d = kt*16 + h8 + j ----
    V8 w1f[4];
#pragma unroll
    for (int kt = 0; kt < 4; ++kt)
#pragma unroll
        for (int j = 0; j < 8; ++j)
            w1f[kt].v8[j] = (f16)W1[(kt * 16 + h8 + j) * 32 + nl];

    // ---- p packed to match prod-frag element order (for fdot2) ----
    f16x2 pp[16];
#pragma unroll
    for (int kt = 0; kt < 4; ++kt)
#pragma unroll
        for (int m = 0; m < 4; ++m) {
            f16x2 t2 = { (f16)p[kt * 16 + h8 + 2 * m], (f16)p[kt * 16 + h8 + 2 * m + 1] };
            pp[kt * 4 + m] = t2;
        }

    // ---- b1 as persistent C-frag (row a = (r&3)+8*(r>>2)+4*hh), w2 per row ----
    fx16 b1C;
    float w2v[16];
#pragma unroll
    for (int r = 0; r < 16; ++r) {
        int a = (r & 3) + 8 * (r >> 2) + 4 * hh;
        b1C[r] = b1[a];
        w2v[r] = w2[a];
    }

    // ---- xi frags for row nl (held in regs for phases A+B) ----
    f16x4 xif[8];
#pragma unroll
    for (int kt = 0; kt < 4; ++kt) {
        const f16* src = Xs + nl * STR + kt * 16 + h8;
        xif[2 * kt]     = *(const f16x4*)(src);
        xif[2 * kt + 1] = *(const f16x4*)(src + 4);
    }

    float accW = 0.f, accWS = 0.f;

    auto body = [&](const f16x4* xi, int jrow, bool valid) {
        const f16* base = Xs + jrow * STR + h8;
        V8 pr[4];
#pragma unroll
        for (int kt = 0; kt < 4; ++kt) {
            f16x4 a0 = *(const f16x4*)(base + kt * 16);
            f16x4 a1 = *(const f16x4*)(base + kt * 16 + 4);
            pr[kt].v4[0] = xi[2 * kt] * a0;       // v_pk_mul_f16
            pr[kt].v4[1] = xi[2 * kt + 1] * a1;
        }
        // h = W1^T prod + b1 : chain C from persistent b1 frag (no init movs)
        fx16 C = __builtin_amdgcn_mfma_f32_32x32x16_f16(w1f[0].v8, pr[0].v8, b1C, 0, 0, 0);
        C = __builtin_amdgcn_mfma_f32_32x32x16_f16(w1f[1].v8, pr[1].v8, C, 0, 0, 0);
        C = __builtin_amdgcn_mfma_f32_32x32x16_f16(w1f[2].v8, pr[2].v8, C, 0, 0, 0);
        C = __builtin_amdgcn_mfma_f32_32x32x16_f16(w1f[3].v8, pr[3].v8, C, 0, 0, 0);
        // s_p partial over this half's 32 d's
        float sp = 0.f;
#pragma unroll
        for (int kt = 0; kt < 4; ++kt)
#pragma unroll
            for (int m = 0; m < 4; ++m)
                sp = __builtin_amdgcn_fdot2(pr[kt].v2[m], pp[kt * 4 + m], sp, false);
        // logit partial: relu(h)·w2 over this half's 16 a-rows (fp32, 2 trees)
        float l0 = 0.f, l1 = 0.f;
#pragma unroll
        for (int r = 0; r < 8; ++r) {
            l0 = fmaf(fmaxf(C[2 * r], 0.f),     w2v[2 * r],     l0);
            l1 = fmaf(fmaxf(C[2 * r + 1], 0.f), w2v[2 * r + 1], l1);
        }
        float l = l0 + l1;
        l  += __shfl_xor(l, 32);    // combine a-halves
        sp += __shfl_xor(sp, 32);   // combine k-halves
        float w = valid ? __expf(l) : 0.f;   // max-free softmax (|l| small)
        accW += w;
        accWS = fmaf(w, sp, accWS);
    };

    // Phase A: 32-triangle via rotation (t=1..15 full, t=16 half)
    for (int t = 1; t <= 16; ++t)
        body(xif, (nl + t) & 31, (t < 16) | (nl < 16));

    // Phase B: i = nl < 32 <= j, broadcast xj
    for (int u = 0; u < 8; ++u)
        body(xif, 32 + u, true);

    // Phase C: 28 pairs among fields 32..39 (lanes nl<28)
    {
        int q = nl < 28 ? nl : 27;
        float disc = 225.0f - 8.0f * (float)q;
        int ii = (int)((15.0f - sqrtf(disc)) * 0.5f);
        if (ii * (15 - ii) / 2 > q) --ii;                 // sqrt 1-ulp fixups
        if ((ii + 1) * (14 - ii) / 2 <= q) ++ii;
        int jj = q - ii * (15 - ii) / 2 + ii + 1;
        int iC = 32 + ii, jC = 32 + jj;                   // pair (iC,jC), iC<jC
        f16x4 xi2[8];
#pragma unroll
        for (int kt = 0; kt < 4; ++kt) {
            const f16* src = Xs + iC * STR + kt * 16 + h8;
            xi2[2 * kt]     = *(const f16x4*)(src);
            xi2[2 * kt + 1] = *(const f16x4*)(src + 4);
        }
        body(xi2, jC, nl < 28);
    }

    // reduce across the 32 columns (halves already identical)
#pragma unroll
    for (int m = 16; m >= 1; m >>= 1) {
        accW  += __shfl_xor(accW, m);
        accWS += __shfl_xor(accWS, m);
    }
    if (lane == 0) out[b] = accWS / accW;
}

extern "C" void kernel_launch(void* const* d_in, const int* in_sizes, int n_in,
                              void* d_out, int out_size, void* d_ws, size_t ws_size,
                              hipStream_t stream) {
    const float* x  = (const float*)d_in[0];
    const float* W1 = (const float*)d_in[1];
    const float* b1 = (const float*)d_in[2];
    const float* w2 = (const float*)d_in[3];
    const float* p  = (const float*)d_in[4];
    float* out = (float*)d_out;
    dim3 grid(NB / 4), block(256);
    hipLaunchKernelGGL(afm_kernel, grid, block, 0, stream, x, W1, b1, w2, p, out);
}